// Round 6
// baseline (249.996 us; speedup 1.0000x reference)
//
#include <hip/hip_runtime.h>
#include <stdint.h>

// Qatten_Weight — Round 6: R5 structure with the aF scratch-spill fixed.
// R5's P4h indexed aF[nh*4*2+...] (runtime) -> whole aF array went to scratch
// (VGPR=52, WRITE_SIZE 33MB). Fix: static unroll over all 8 agents, predicate
// the LDS write by wave. Everything else R5-verbatim.
// B=16384 A=8 S=512 U=64 H=4 E=64 HE=256; BT=32, grid 512 x 256 threads.

typedef __attribute__((ext_vector_type(8))) short short8v;  // 8 bf16
typedef __attribute__((ext_vector_type(4))) float f32x4;

constexpr int BB = 16384, AA = 8, SS = 512, UU = 64, HH = 4, EE = 64, HE = 256;
constexpr int BT = 32;
constexpr int OUTV = BB * AA, OUTR = OUTV + BB, OUTE = OUTR + 1;

// packed fragment regions in ws (bf16 element offsets); frag = 512 elems = 1KB
constexpr int OFF_W1F  = 0;        // sel_w1: frag = h*256 + ftile*16 + kf   (1024)
constexpr int OFF_W2F  = 524288;   // sel_w2: frag = h*32  + etile*8  + kf   (128)
constexpr int OFF_VW1F = 589824;   // v_w1:   frag = etile*16 + kf           (64)
constexpr int OFF_KWF  = 622592;   // key_w:  frag = h*8 + utile*2 + kf      (32)
constexpr int PREP_N   = 638976;

__device__ __forceinline__ unsigned short f2bf(float x) {
  union { float f; uint32_t u; } v; v.f = x;
  uint32_t r = v.u + 0x7fffu + ((v.u >> 16) & 1u);   // RNE
  return (unsigned short)(r >> 16);
}
__device__ __forceinline__ float bf2f(short h) {
  union { uint32_t u; float f; } v; v.u = ((uint32_t)(unsigned short)h) << 16;
  return v.f;
}

// Pack: within a frag, element r = l*8 + j holds B[k = kf*32 + (l>>4)*8 + j]
// [col = tile*16 + (l&15)] — exactly the 16x16x32 B-fragment lane layout.
__global__ __launch_bounds__(256) void prep_kernel(
    const float* __restrict__ w1, const float* __restrict__ w2,
    const float* __restrict__ vw1, const float* __restrict__ kw,
    unsigned short* __restrict__ ws) {
  int idx = blockIdx.x * 256 + threadIdx.x;
  if (idx >= PREP_N) return;
  int r = idx & 511, l = r >> 3, j = r & 7, lr = l & 15, g = l >> 4;
  int fi = idx >> 9;
  float val;
  if (idx < OFF_W2F) {                    // B[k=s][col=f] for P1
    int h = fi >> 8, tl = (fi >> 4) & 15, kf = fi & 15;
    int s = kf * 32 + g * 8 + j, f = tl * 16 + lr;
    val = w1[((size_t)(h * SS) + s) * HE + f];
  } else if (idx < OFF_VW1F) {            // B[k=f][col=e] for P2
    fi -= OFF_W2F >> 9;
    int h = fi >> 5, tl = (fi >> 3) & 3, kf = fi & 7;
    int k = kf * 32 + g * 8 + j, e = tl * 16 + lr;
    val = w2[((size_t)(h * HE) + k) * EE + e];
  } else if (idx < OFF_KWF) {             // B[k=s][col=e] for P1v
    fi -= OFF_VW1F >> 9;
    int tl = fi >> 4, kf = fi & 15;
    int s = kf * 32 + g * 8 + j, e = tl * 16 + lr;
    val = vw1[(size_t)s * EE + e];
  } else {                                // B[k=e][col=u] for P3
    fi -= OFF_KWF >> 9;
    int h = fi >> 3, tl = (fi >> 1) & 3, kf = fi & 1;
    int k = kf * 32 + g * 8 + j, u = tl * 16 + lr;
    val = kw[((size_t)(h * UU) + u) * EE + k];
  }
  ws[idx] = f2bf(val);
}

__global__ __launch_bounds__(256, 3) void qatten_mfma(
    const float* __restrict__ states, const float* __restrict__ sel_b1,
    const float* __restrict__ v_b1,  const float* __restrict__ v_w2,
    const float* __restrict__ v_b2,  const unsigned short* __restrict__ ws,
    float* __restrict__ out) {
  __shared__ __align__(16) unsigned char lds[39168];
  short* hmid = (short*)lds;                 // [32][264] bf16  (16896 B)
  short* sel  = (short*)(lds + 16896);       // [32][72]  bf16  ( 4608 B)
  short* mh   = (short*)(lds + 21504);       // [32][72]  bf16  ( 4608 B)
  short* vhid = (short*)(lds + 26112);       // [32][72]  bf16  ( 4608 B)
  float* logitsL = (float*)(lds + 30720);    // [32][33] f32    ( 4224 B)
  float* wtsL    = (float*)(lds + 34944);    // [32][33] f32    ( 4224 B)

  const int t  = threadIdx.x;
  const int w  = t >> 6, l = t & 63;
  const int mt = w & 1, nh = w >> 1;         // M-tile, N-half (R2/R4 mapping)
  const int lr = l & 15, g = l >> 4;
  const int b0 = blockIdx.x * BT;
  const short* w1f  = (const short*)ws + OFF_W1F;
  const short* w2f  = (const short*)ws + OFF_W2F;
  const short* vw1f = (const short*)ws + OFF_VW1F;
  const short* kwf  = (const short*)ws + OFF_KWF;

  // ---- A-fragments: 16 rows of st, bf16, in registers (R2/R4 verbatim) ----
  short8v aF[16];
  {
    const float* srow = states + (size_t)(b0 + mt * 16 + lr) * (AA * SS);
    #pragma unroll
    for (int f = 0; f < 16; ++f) {
      float4 p0 = *(const float4*)(srow + f * 32 + g * 8);
      float4 p1 = *(const float4*)(srow + f * 32 + g * 8 + 4);
      short8v a;
      a[0] = (short)f2bf(p0.x); a[1] = (short)f2bf(p0.y);
      a[2] = (short)f2bf(p0.z); a[3] = (short)f2bf(p0.w);
      a[4] = (short)f2bf(p1.x); a[5] = (short)f2bf(p1.y);
      a[6] = (short)f2bf(p1.z); a[7] = (short)f2bf(p1.w);
      aF[f] = a;
    }
  }

  for (int h = 0; h < HH; ++h) {
    // ---- P1: hmid = relu(st @ sel_w1[h] + b1); K-outer, 8 indep accs ----
    f32x4 acc[8] = {{0,0,0,0},{0,0,0,0},{0,0,0,0},{0,0,0,0},
                    {0,0,0,0},{0,0,0,0},{0,0,0,0},{0,0,0,0}};
    {
      const short* bb = w1f + ((size_t)(h * 256 + nh * 128)) * 512 + l * 8;
      #pragma unroll
      for (int kf = 0; kf < 16; ++kf) {
        short8v af = aF[kf];
        #pragma unroll
        for (int tl = 0; tl < 8; ++tl)
          acc[tl] = __builtin_amdgcn_mfma_f32_16x16x32_bf16(
              af, *(const short8v*)(bb + (size_t)(tl * 16 + kf) * 512),
              acc[tl], 0, 0, 0);
      }
    }
    #pragma unroll
    for (int tl = 0; tl < 8; ++tl) {
      int fb = (nh * 8 + tl) * 16;
      float bias = sel_b1[h * HE + fb + lr];
      #pragma unroll
      for (int r2 = 0; r2 < 4; ++r2)
        hmid[(mt * 16 + g * 4 + r2) * 264 + fb + lr] =
            (short)f2bf(fmaxf(acc[tl][r2] + bias, 0.f));
    }
    __syncthreads();

    // ---- P2: sel = hmid @ sel_w2[h]; K-outer, 2 indep accs, K=256 ----
    f32x4 a2[2] = {{0,0,0,0},{0,0,0,0}};
    {
      const short* ah = hmid + (mt * 16 + lr) * 264 + g * 8;
      const short* b2 = w2f + ((size_t)(h * 32 + nh * 16)) * 512 + l * 8;
      #pragma unroll
      for (int kf = 0; kf < 8; ++kf) {
        short8v af = *(const short8v*)(ah + kf * 32);
        #pragma unroll
        for (int tl = 0; tl < 2; ++tl)
          a2[tl] = __builtin_amdgcn_mfma_f32_16x16x32_bf16(
              af, *(const short8v*)(b2 + (size_t)(tl * 8 + kf) * 512),
              a2[tl], 0, 0, 0);
      }
    }
    #pragma unroll
    for (int tl = 0; tl < 2; ++tl)
      #pragma unroll
      for (int r2 = 0; r2 < 4; ++r2)
        sel[(mt * 16 + g * 4 + r2) * 72 + (nh * 2 + tl) * 16 + lr] =
            (short)f2bf(a2[tl][r2]);
    __syncthreads();

    // ---- P3: m = sel @ key_w[h]^T; K-outer, 2 indep accs, K=64 ----
    f32x4 a3[2] = {{0,0,0,0},{0,0,0,0}};
    {
      const short* as = sel + (mt * 16 + lr) * 72 + g * 8;
      const short* b3 = kwf + ((size_t)(h * 8 + nh * 4)) * 512 + l * 8;
      #pragma unroll
      for (int kf = 0; kf < 2; ++kf) {
        short8v af = *(const short8v*)(as + kf * 32);
        #pragma unroll
        for (int tl = 0; tl < 2; ++tl)
          a3[tl] = __builtin_amdgcn_mfma_f32_16x16x32_bf16(
              af, *(const short8v*)(b3 + (size_t)(tl * 2 + kf) * 512),
              a3[tl], 0, 0, 0);
      }
    }
    #pragma unroll
    for (int tl = 0; tl < 2; ++tl)
      #pragma unroll
      for (int r2 = 0; r2 < 4; ++r2)
        mh[(mt * 16 + g * 4 + r2) * 72 + (nh * 2 + tl) * 16 + lr] =
            (short)f2bf(a3[tl][r2]);
    __syncthreads();

    // ---- P4h: logits from registers; ALL indices into aF are literals ----
    // lane (lr,g) of wave (mt,nh): row b = mt*16+lr. Each wave computes all
    // 8 agents (static aF indices); only the owning wave (a>>2 == nh) writes.
    {
      const short* mrow = mh + (mt * 16 + lr) * 72;
      short8v mv0 = *(const short8v*)(mrow + g * 8);
      short8v mv1 = *(const short8v*)(mrow + 32 + g * 8);
      #pragma unroll
      for (int a = 0; a < 8; ++a) {          // 'a' is compile-time constant
        short8v a0 = aF[a * 2], a1 = aF[a * 2 + 1];
        float p = 0.f;
        #pragma unroll
        for (int j = 0; j < 8; ++j)
          p += bf2f(a0[j]) * bf2f(mv0[j]) + bf2f(a1[j]) * bf2f(mv1[j]);
        p += __shfl_xor(p, 16);
        p += __shfl_xor(p, 32);
        if (g == 0 && (a >> 2) == nh)
          logitsL[(mt * 16 + lr) * 33 + h * 8 + a] = p;
      }
    }
    // no barrier needed: next P1 writes hmid (last read 2 barriers ago);
    // mh next written by next P3, which is 2 barriers away.
  }

  // ---- P1v: vhid = relu(st @ v_w1 + b1); K-outer, 2 indep accs ----
  {
    f32x4 av[2] = {{0,0,0,0},{0,0,0,0}};
    const short* bv = vw1f + ((size_t)(nh * 32)) * 512 + l * 8;
    #pragma unroll
    for (int kf = 0; kf < 16; ++kf) {
      short8v af = aF[kf];
      #pragma unroll
      for (int tl = 0; tl < 2; ++tl)
        av[tl] = __builtin_amdgcn_mfma_f32_16x16x32_bf16(
            af, *(const short8v*)(bv + (size_t)(tl * 16 + kf) * 512),
            av[tl], 0, 0, 0);
    }
    #pragma unroll
    for (int tl = 0; tl < 2; ++tl) {
      int eb = (nh * 2 + tl) * 16;
      float bias = v_b1[eb + lr];
      #pragma unroll
      for (int r2 = 0; r2 < 4; ++r2)
        vhid[(mt * 16 + g * 4 + r2) * 72 + eb + lr] =
            (short)f2bf(fmaxf(av[tl][r2] + bias, 0.f));
    }
  }
  __syncthreads();

  // ---- v finalize (reads vhid) ----
  {
    int b = t >> 3, r = t & 7;
    short8v hv = *(const short8v*)(vhid + b * 72 + r * 8);
    float p = 0.f;
    #pragma unroll
    for (int j = 0; j < 8; ++j) p += bf2f(hv[j]) * v_w2[r * 8 + j];
    p += __shfl_xor(p, 1); p += __shfl_xor(p, 2); p += __shfl_xor(p, 4);
    if (r == 0) out[OUTV + b0 + b] = p + v_b2[0];
  }
  __syncthreads();

  // ---- P5: softmax, entropy, reg (R2/R4 verbatim) ----
  if (t < 128) {
    int b = t >> 2, hh = t & 3;
    float sc[8];
    float rp = 0.f, mx = -1e30f;
    #pragma unroll
    for (int a = 0; a < 8; ++a) {
      float lg = logitsL[b * 33 + hh * 8 + a];
      rp += lg * lg;
      sc[a] = lg * 0.125f;
      mx = fmaxf(mx, sc[a]);
    }
    float sum = 0.f;
    #pragma unroll
    for (int a = 0; a < 8; ++a) { sc[a] = __expf(sc[a] - mx); sum += sc[a]; }
    float inv = 1.f / sum, ent = 0.f;
    #pragma unroll
    for (int a = 0; a < 8; ++a) {
      float wv = sc[a] * inv;
      wtsL[b * 33 + hh * 8 + a] = wv;
      ent += wv * __logf(wv + 1e-8f);
    }
    #pragma unroll
    for (int off = 1; off <= 32; off <<= 1) rp += __shfl_xor(rp, off);
    if ((t & 63) == 0)
      atomicAdd(out + OUTR, rp * (0.001f / ((float)BB * (float)AA)));
    float ep = ent;
    #pragma unroll
    for (int off = 4; off <= 32; off <<= 1) ep += __shfl_xor(ep, off);
    if ((t & 63) < 4) atomicAdd(out + OUTE + hh, -ep / (float)BB);
  }
  __syncthreads();
  {
    int b = t >> 3, a = t & 7;
    out[(size_t)(b0 + b) * AA + a] = wtsL[b * 33 + a] + wtsL[b * 33 + 8 + a] +
                                     wtsL[b * 33 + 16 + a] + wtsL[b * 33 + 24 + a];
  }
}

extern "C" void kernel_launch(void* const* d_in, const int* in_sizes, int n_in,
                              void* d_out, int out_size, void* d_ws, size_t ws_size,
                              hipStream_t stream) {
  (void)in_sizes; (void)n_in; (void)ws_size; (void)out_size;
  const float* states = (const float*)d_in[1];
  const float* sel_w1 = (const float*)d_in[3];
  const float* sel_b1 = (const float*)d_in[4];
  const float* sel_w2 = (const float*)d_in[5];
  const float* key_w  = (const float*)d_in[6];
  const float* v_w1   = (const float*)d_in[7];
  const float* v_b1   = (const float*)d_in[8];
  const float* v_w2   = (const float*)d_in[9];
  const float* v_b2   = (const float*)d_in[10];
  float* out = (float*)d_out;
  unsigned short* ws = (unsigned short*)d_ws;

  hipMemsetAsync(out + OUTR, 0, 5 * sizeof(float), stream);
  prep_kernel<<<(PREP_N + 255) / 256, 256, 0, stream>>>(sel_w1, sel_w2, v_w1,
                                                        key_w, ws);
  qatten_mfma<<<BB / BT, 256, 0, stream>>>(states, sel_b1, v_b1, v_w2, v_b2,
                                           ws, out);
}

// Round 7
// 198.845 us; speedup vs baseline: 1.2572x; 1.2572x over previous
//
#include <hip/hip_runtime.h>
#include <stdint.h>

// Qatten_Weight — Round 7: R6 with the REAL spill cause fixed.
// R5/R6's __launch_bounds__(256,3) capped VGPR (~170) below the P1 loop's
// peak pressure -> compiler spilled aF to scratch (R6: VGPR=84, 90MB scratch
// writes). Fix 1: plain __launch_bounds__(256). Fix 2: P1 split into two
// 4-tile passes (acc[4]) to halve in-flight B-frags + accumulator pressure.
// Everything else R6-verbatim (LDS 39KB, register P4h with static indices).
// B=16384 A=8 S=512 U=64 H=4 E=64 HE=256; BT=32, grid 512 x 256 threads.

typedef __attribute__((ext_vector_type(8))) short short8v;  // 8 bf16
typedef __attribute__((ext_vector_type(4))) float f32x4;

constexpr int BB = 16384, AA = 8, SS = 512, UU = 64, HH = 4, EE = 64, HE = 256;
constexpr int BT = 32;
constexpr int OUTV = BB * AA, OUTR = OUTV + BB, OUTE = OUTR + 1;

// packed fragment regions in ws (bf16 element offsets); frag = 512 elems = 1KB
constexpr int OFF_W1F  = 0;        // sel_w1: frag = h*256 + ftile*16 + kf   (1024)
constexpr int OFF_W2F  = 524288;   // sel_w2: frag = h*32  + etile*8  + kf   (128)
constexpr int OFF_VW1F = 589824;   // v_w1:   frag = etile*16 + kf           (64)
constexpr int OFF_KWF  = 622592;   // key_w:  frag = h*8 + utile*2 + kf      (32)
constexpr int PREP_N   = 638976;

__device__ __forceinline__ unsigned short f2bf(float x) {
  union { float f; uint32_t u; } v; v.f = x;
  uint32_t r = v.u + 0x7fffu + ((v.u >> 16) & 1u);   // RNE
  return (unsigned short)(r >> 16);
}
__device__ __forceinline__ float bf2f(short h) {
  union { uint32_t u; float f; } v; v.u = ((uint32_t)(unsigned short)h) << 16;
  return v.f;
}

// Pack: within a frag, element r = l*8 + j holds B[k = kf*32 + (l>>4)*8 + j]
// [col = tile*16 + (l&15)] — exactly the 16x16x32 B-fragment lane layout.
__global__ __launch_bounds__(256) void prep_kernel(
    const float* __restrict__ w1, const float* __restrict__ w2,
    const float* __restrict__ vw1, const float* __restrict__ kw,
    unsigned short* __restrict__ ws) {
  int idx = blockIdx.x * 256 + threadIdx.x;
  if (idx >= PREP_N) return;
  int r = idx & 511, l = r >> 3, j = r & 7, lr = l & 15, g = l >> 4;
  int fi = idx >> 9;
  float val;
  if (idx < OFF_W2F) {                    // B[k=s][col=f] for P1
    int h = fi >> 8, tl = (fi >> 4) & 15, kf = fi & 15;
    int s = kf * 32 + g * 8 + j, f = tl * 16 + lr;
    val = w1[((size_t)(h * SS) + s) * HE + f];
  } else if (idx < OFF_VW1F) {            // B[k=f][col=e] for P2
    fi -= OFF_W2F >> 9;
    int h = fi >> 5, tl = (fi >> 3) & 3, kf = fi & 7;
    int k = kf * 32 + g * 8 + j, e = tl * 16 + lr;
    val = w2[((size_t)(h * HE) + k) * EE + e];
  } else if (idx < OFF_KWF) {             // B[k=s][col=e] for P1v
    fi -= OFF_VW1F >> 9;
    int tl = fi >> 4, kf = fi & 15;
    int s = kf * 32 + g * 8 + j, e = tl * 16 + lr;
    val = vw1[(size_t)s * EE + e];
  } else {                                // B[k=e][col=u] for P3
    fi -= OFF_KWF >> 9;
    int h = fi >> 3, tl = (fi >> 1) & 3, kf = fi & 1;
    int k = kf * 32 + g * 8 + j, u = tl * 16 + lr;
    val = kw[((size_t)(h * UU) + u) * EE + k];
  }
  ws[idx] = f2bf(val);
}

__global__ __launch_bounds__(256) void qatten_mfma(
    const float* __restrict__ states, const float* __restrict__ sel_b1,
    const float* __restrict__ v_b1,  const float* __restrict__ v_w2,
    const float* __restrict__ v_b2,  const unsigned short* __restrict__ ws,
    float* __restrict__ out) {
  __shared__ __align__(16) unsigned char lds[39168];
  short* hmid = (short*)lds;                 // [32][264] bf16  (16896 B)
  short* sel  = (short*)(lds + 16896);       // [32][72]  bf16  ( 4608 B)
  short* mh   = (short*)(lds + 21504);       // [32][72]  bf16  ( 4608 B)
  short* vhid = (short*)(lds + 26112);       // [32][72]  bf16  ( 4608 B)
  float* logitsL = (float*)(lds + 30720);    // [32][33] f32    ( 4224 B)
  float* wtsL    = (float*)(lds + 34944);    // [32][33] f32    ( 4224 B)

  const int t  = threadIdx.x;
  const int w  = t >> 6, l = t & 63;
  const int mt = w & 1, nh = w >> 1;         // M-tile, N-half (R2/R4 mapping)
  const int lr = l & 15, g = l >> 4;
  const int b0 = blockIdx.x * BT;
  const short* w1f  = (const short*)ws + OFF_W1F;
  const short* w2f  = (const short*)ws + OFF_W2F;
  const short* vw1f = (const short*)ws + OFF_VW1F;
  const short* kwf  = (const short*)ws + OFF_KWF;

  // ---- A-fragments: 16 rows of st, bf16, in registers (R2/R4 verbatim) ----
  short8v aF[16];
  {
    const float* srow = states + (size_t)(b0 + mt * 16 + lr) * (AA * SS);
    #pragma unroll
    for (int f = 0; f < 16; ++f) {
      float4 p0 = *(const float4*)(srow + f * 32 + g * 8);
      float4 p1 = *(const float4*)(srow + f * 32 + g * 8 + 4);
      short8v a;
      a[0] = (short)f2bf(p0.x); a[1] = (short)f2bf(p0.y);
      a[2] = (short)f2bf(p0.z); a[3] = (short)f2bf(p0.w);
      a[4] = (short)f2bf(p1.x); a[5] = (short)f2bf(p1.y);
      a[6] = (short)f2bf(p1.z); a[7] = (short)f2bf(p1.w);
      aF[f] = a;
    }
  }

  for (int h = 0; h < HH; ++h) {
    // ---- P1: hmid = relu(st @ sel_w1[h] + b1); two 4-tile passes ----
    #pragma unroll
    for (int half = 0; half < 2; ++half) {
      f32x4 acc[4] = {{0,0,0,0},{0,0,0,0},{0,0,0,0},{0,0,0,0}};
      const short* bb =
          w1f + ((size_t)(h * 256 + nh * 128 + half * 64)) * 512 + l * 8;
      #pragma unroll
      for (int kf = 0; kf < 16; ++kf) {
        short8v af = aF[kf];
        #pragma unroll
        for (int tl = 0; tl < 4; ++tl)
          acc[tl] = __builtin_amdgcn_mfma_f32_16x16x32_bf16(
              af, *(const short8v*)(bb + (size_t)(tl * 16 + kf) * 512),
              acc[tl], 0, 0, 0);
      }
      #pragma unroll
      for (int tl = 0; tl < 4; ++tl) {
        int fb = (nh * 8 + half * 4 + tl) * 16;
        float bias = sel_b1[h * HE + fb + lr];
        #pragma unroll
        for (int r2 = 0; r2 < 4; ++r2)
          hmid[(mt * 16 + g * 4 + r2) * 264 + fb + lr] =
              (short)f2bf(fmaxf(acc[tl][r2] + bias, 0.f));
      }
    }
    __syncthreads();

    // ---- P2: sel = hmid @ sel_w2[h]; K-outer, 2 indep accs, K=256 ----
    f32x4 a2[2] = {{0,0,0,0},{0,0,0,0}};
    {
      const short* ah = hmid + (mt * 16 + lr) * 264 + g * 8;
      const short* b2 = w2f + ((size_t)(h * 32 + nh * 16)) * 512 + l * 8;
      #pragma unroll
      for (int kf = 0; kf < 8; ++kf) {
        short8v af = *(const short8v*)(ah + kf * 32);
        #pragma unroll
        for (int tl = 0; tl < 2; ++tl)
          a2[tl] = __builtin_amdgcn_mfma_f32_16x16x32_bf16(
              af, *(const short8v*)(b2 + (size_t)(tl * 8 + kf) * 512),
              a2[tl], 0, 0, 0);
      }
    }
    #pragma unroll
    for (int tl = 0; tl < 2; ++tl)
      #pragma unroll
      for (int r2 = 0; r2 < 4; ++r2)
        sel[(mt * 16 + g * 4 + r2) * 72 + (nh * 2 + tl) * 16 + lr] =
            (short)f2bf(a2[tl][r2]);
    __syncthreads();

    // ---- P3: m = sel @ key_w[h]^T; K-outer, 2 indep accs, K=64 ----
    f32x4 a3[2] = {{0,0,0,0},{0,0,0,0}};
    {
      const short* as = sel + (mt * 16 + lr) * 72 + g * 8;
      const short* b3 = kwf + ((size_t)(h * 8 + nh * 4)) * 512 + l * 8;
      #pragma unroll
      for (int kf = 0; kf < 2; ++kf) {
        short8v af = *(const short8v*)(as + kf * 32);
        #pragma unroll
        for (int tl = 0; tl < 2; ++tl)
          a3[tl] = __builtin_amdgcn_mfma_f32_16x16x32_bf16(
              af, *(const short8v*)(b3 + (size_t)(tl * 2 + kf) * 512),
              a3[tl], 0, 0, 0);
      }
    }
    #pragma unroll
    for (int tl = 0; tl < 2; ++tl)
      #pragma unroll
      for (int r2 = 0; r2 < 4; ++r2)
        mh[(mt * 16 + g * 4 + r2) * 72 + (nh * 2 + tl) * 16 + lr] =
            (short)f2bf(a3[tl][r2]);
    __syncthreads();

    // ---- P4h: logits from registers; ALL indices into aF are literals ----
    {
      const short* mrow = mh + (mt * 16 + lr) * 72;
      short8v mv0 = *(const short8v*)(mrow + g * 8);
      short8v mv1 = *(const short8v*)(mrow + 32 + g * 8);
      #pragma unroll
      for (int a = 0; a < 8; ++a) {          // 'a' is compile-time constant
        short8v a0 = aF[a * 2], a1 = aF[a * 2 + 1];
        float p = 0.f;
        #pragma unroll
        for (int j = 0; j < 8; ++j)
          p += bf2f(a0[j]) * bf2f(mv0[j]) + bf2f(a1[j]) * bf2f(mv1[j]);
        p += __shfl_xor(p, 16);
        p += __shfl_xor(p, 32);
        if (g == 0 && (a >> 2) == nh)
          logitsL[(mt * 16 + lr) * 33 + h * 8 + a] = p;
      }
    }
    // no barrier needed: next P1 writes hmid (last read 2 barriers ago);
    // mh next written by next P3, which is 2 barriers away.
  }

  // ---- P1v: vhid = relu(st @ v_w1 + b1); K-outer, 2 indep accs ----
  {
    f32x4 av[2] = {{0,0,0,0},{0,0,0,0}};
    const short* bv = vw1f + ((size_t)(nh * 32)) * 512 + l * 8;
    #pragma unroll
    for (int kf = 0; kf < 16; ++kf) {
      short8v af = aF[kf];
      #pragma unroll
      for (int tl = 0; tl < 2; ++tl)
        av[tl] = __builtin_amdgcn_mfma_f32_16x16x32_bf16(
            af, *(const short8v*)(bv + (size_t)(tl * 16 + kf) * 512),
            av[tl], 0, 0, 0);
    }
    #pragma unroll
    for (int tl = 0; tl < 2; ++tl) {
      int eb = (nh * 2 + tl) * 16;
      float bias = v_b1[eb + lr];
      #pragma unroll
      for (int r2 = 0; r2 < 4; ++r2)
        vhid[(mt * 16 + g * 4 + r2) * 72 + eb + lr] =
            (short)f2bf(fmaxf(av[tl][r2] + bias, 0.f));
    }
  }
  __syncthreads();

  // ---- v finalize (reads vhid) ----
  {
    int b = t >> 3, r = t & 7;
    short8v hv = *(const short8v*)(vhid + b * 72 + r * 8);
    float p = 0.f;
    #pragma unroll
    for (int j = 0; j < 8; ++j) p += bf2f(hv[j]) * v_w2[r * 8 + j];
    p += __shfl_xor(p, 1); p += __shfl_xor(p, 2); p += __shfl_xor(p, 4);
    if (r == 0) out[OUTV + b0 + b] = p + v_b2[0];
  }
  __syncthreads();

  // ---- P5: softmax, entropy, reg (R2/R4 verbatim) ----
  if (t < 128) {
    int b = t >> 2, hh = t & 3;
    float sc[8];
    float rp = 0.f, mx = -1e30f;
    #pragma unroll
    for (int a = 0; a < 8; ++a) {
      float lg = logitsL[b * 33 + hh * 8 + a];
      rp += lg * lg;
      sc[a] = lg * 0.125f;
      mx = fmaxf(mx, sc[a]);
    }
    float sum = 0.f;
    #pragma unroll
    for (int a = 0; a < 8; ++a) { sc[a] = __expf(sc[a] - mx); sum += sc[a]; }
    float inv = 1.f / sum, ent = 0.f;
    #pragma unroll
    for (int a = 0; a < 8; ++a) {
      float wv = sc[a] * inv;
      wtsL[b * 33 + hh * 8 + a] = wv;
      ent += wv * __logf(wv + 1e-8f);
    }
    #pragma unroll
    for (int off = 1; off <= 32; off <<= 1) rp += __shfl_xor(rp, off);
    if ((t & 63) == 0)
      atomicAdd(out + OUTR, rp * (0.001f / ((float)BB * (float)AA)));
    float ep = ent;
    #pragma unroll
    for (int off = 4; off <= 32; off <<= 1) ep += __shfl_xor(ep, off);
    if ((t & 63) < 4) atomicAdd(out + OUTE + hh, -ep / (float)BB);
  }
  __syncthreads();
  {
    int b = t >> 3, a = t & 7;
    out[(size_t)(b0 + b) * AA + a] = wtsL[b * 33 + a] + wtsL[b * 33 + 8 + a] +
                                     wtsL[b * 33 + 16 + a] + wtsL[b * 33 + 24 + a];
  }
}

extern "C" void kernel_launch(void* const* d_in, const int* in_sizes, int n_in,
                              void* d_out, int out_size, void* d_ws, size_t ws_size,
                              hipStream_t stream) {
  (void)in_sizes; (void)n_in; (void)ws_size; (void)out_size;
  const float* states = (const float*)d_in[1];
  const float* sel_w1 = (const float*)d_in[3];
  const float* sel_b1 = (const float*)d_in[4];
  const float* sel_w2 = (const float*)d_in[5];
  const float* key_w  = (const float*)d_in[6];
  const float* v_w1   = (const float*)d_in[7];
  const float* v_b1   = (const float*)d_in[8];
  const float* v_w2   = (const float*)d_in[9];
  const float* v_b2   = (const float*)d_in[10];
  float* out = (float*)d_out;
  unsigned short* ws = (unsigned short*)d_ws;

  hipMemsetAsync(out + OUTR, 0, 5 * sizeof(float), stream);
  prep_kernel<<<(PREP_N + 255) / 256, 256, 0, stream>>>(sel_w1, sel_w2, v_w1,
                                                        key_w, ws);
  qatten_mfma<<<BB / BT, 256, 0, stream>>>(states, sel_b1, v_b1, v_w2, v_b2,
                                           ws, out);
}

// Round 8
// 133.298 us; speedup vs baseline: 1.8755x; 1.4917x over previous
//
#include <hip/hip_runtime.h>
#include <stdint.h>

// Qatten_Weight — Round 8: LDS-staged B pipeline (latency fix).
// R4/R7 evidence: kernel is L2-latency-bound (all pipes <6% busy); per-wave
// direct B-loads pay ~225cyc each. New structure: BT=64, grid 256, 4 waves =
// 4 M-tiles; sel_w1 staged f-tile-by-f-tile (16KB) into LDS (reg-staged,
// depth-1 pipelined: next tile's global loads issue under current tile's
// MFMAs). All waves share each staged tile (4x reuse). hmid half-width with
// P2 accumulating across 2 K-halves. Phases P2/P3/P4h/P5 = proven R4/R7 math.
// B=16384 A=8 S=512 U=64 H=4 E=64 HE=256.

typedef __attribute__((ext_vector_type(8))) short short8v;  // 8 bf16
typedef __attribute__((ext_vector_type(4))) float f32x4;

constexpr int BB = 16384, AA = 8, SS = 512, UU = 64, HH = 4, EE = 64, HE = 256;
constexpr int BT = 64;
constexpr int OUTV = BB * AA, OUTR = OUTV + BB, OUTE = OUTR + 1;

// packed fragment regions in ws (bf16 element offsets); frag = 512 elems = 1KB
constexpr int OFF_W1F  = 0;        // sel_w1: frag = h*256 + ftile*16 + kf   (1024)
constexpr int OFF_W2F  = 524288;   // sel_w2: frag = h*32  + etile*8  + kf   (128)
constexpr int OFF_VW1F = 589824;   // v_w1:   frag = etile*16 + kf           (64)
constexpr int OFF_KWF  = 622592;   // key_w:  frag = h*8 + utile*2 + kf      (32)
constexpr int PREP_N   = 638976;

__device__ __forceinline__ unsigned short f2bf(float x) {
  union { float f; uint32_t u; } v; v.f = x;
  uint32_t r = v.u + 0x7fffu + ((v.u >> 16) & 1u);   // RNE
  return (unsigned short)(r >> 16);
}
__device__ __forceinline__ float bf2f(short h) {
  union { uint32_t u; float f; } v; v.u = ((uint32_t)(unsigned short)h) << 16;
  return v.f;
}

// Pack: within a frag, element r = l*8 + j holds B[k = kf*32 + (l>>4)*8 + j]
// [col = tile*16 + (l&15)] — the 16x16x32 B-fragment lane layout. (unchanged)
__global__ __launch_bounds__(256) void prep_kernel(
    const float* __restrict__ w1, const float* __restrict__ w2,
    const float* __restrict__ vw1, const float* __restrict__ kw,
    unsigned short* __restrict__ ws) {
  int idx = blockIdx.x * 256 + threadIdx.x;
  if (idx >= PREP_N) return;
  int r = idx & 511, l = r >> 3, j = r & 7, lr = l & 15, g = l >> 4;
  int fi = idx >> 9;
  float val;
  if (idx < OFF_W2F) {                    // B[k=s][col=f] for P1
    int h = fi >> 8, tl = (fi >> 4) & 15, kf = fi & 15;
    int s = kf * 32 + g * 8 + j, f = tl * 16 + lr;
    val = w1[((size_t)(h * SS) + s) * HE + f];
  } else if (idx < OFF_VW1F) {            // B[k=f][col=e] for P2
    fi -= OFF_W2F >> 9;
    int h = fi >> 5, tl = (fi >> 3) & 3, kf = fi & 7;
    int k = kf * 32 + g * 8 + j, e = tl * 16 + lr;
    val = w2[((size_t)(h * HE) + k) * EE + e];
  } else if (idx < OFF_KWF) {             // B[k=s][col=e] for P1v
    fi -= OFF_VW1F >> 9;
    int tl = fi >> 4, kf = fi & 15;
    int s = kf * 32 + g * 8 + j, e = tl * 16 + lr;
    val = vw1[(size_t)s * EE + e];
  } else {                                // B[k=e][col=u] for P3
    fi -= OFF_KWF >> 9;
    int h = fi >> 3, tl = (fi >> 1) & 3, kf = fi & 1;
    int k = kf * 32 + g * 8 + j, u = tl * 16 + lr;
    val = kw[((size_t)(h * UU) + u) * EE + k];
  }
  ws[idx] = f2bf(val);
}

#define P1_LOAD(dst, FT)                                                 \
  do {                                                                   \
    const short* ns_ = w1h + (size_t)((FT) * 16) * 512;                  \
    _Pragma("unroll")                                                    \
    for (int q = 0; q < 4; ++q)                                          \
      dst[q] = *(const short8v*)(ns_ + (size_t)(q * 256 + t) * 8);       \
  } while (0)

#define P1_WRITE(src)                                                    \
  do {                                                                   \
    _Pragma("unroll")                                                    \
    for (int q = 0; q < 4; ++q)                                          \
      *(short8v*)(Bst + (q * 256 + t) * 8) = src[q];                     \
  } while (0)

#define P1_COMPUTE(FT)                                                   \
  do {                                                                   \
    f32x4 ap[4] = {{0,0,0,0},{0,0,0,0},{0,0,0,0},{0,0,0,0}};             \
    _Pragma("unroll")                                                    \
    for (int kf = 0; kf < 16; ++kf)                                      \
      ap[kf & 3] = __builtin_amdgcn_mfma_f32_16x16x32_bf16(              \
          aF[kf], *(const short8v*)(Bst + kf * 512 + l * 8),             \
          ap[kf & 3], 0, 0, 0);                                          \
    int fb = (hf * 8 + (FT)) * 16;                                       \
    float bias = sel_b1[h * HE + fb + lr];                               \
    _Pragma("unroll")                                                    \
    for (int r2 = 0; r2 < 4; ++r2) {                                     \
      float vv = ap[0][r2] + ap[1][r2] + ap[2][r2] + ap[3][r2] + bias;   \
      hmid[(w * 16 + g * 4 + r2) * 136 + (FT) * 16 + lr] =               \
          (short)f2bf(fmaxf(vv, 0.f));                                   \
    }                                                                    \
  } while (0)

__global__ __launch_bounds__(256) void qatten_mfma(
    const float* __restrict__ states, const float* __restrict__ sel_b1,
    const float* __restrict__ v_b1,  const float* __restrict__ v_w2,
    const float* __restrict__ v_b2,  const unsigned short* __restrict__ ws,
    float* __restrict__ out) {
  __shared__ __align__(16) unsigned char lds[60672];
  short* Bst  = (short*)lds;                 // 16384 B staged B f-tile
  short* hmid = (short*)(lds + 16384);       // [64][136] bf16 (17408 B) half-HE
  short* sel  = (short*)(lds + 33792);       // [64][72]  bf16 ( 9216 B)
  short* mh   = (short*)(lds + 43008);       // [64][72]  bf16 ( 9216 B)
  float* logitsL = (float*)(lds + 52224);    // [64][33] f32   ( 8448 B)
  float* wtsL = (float*)(lds + 43008);       // alias mh (dead after P4h)
  short* vhid = sel;                         // alias sel (dead after last P3)

  const int t = threadIdx.x, w = t >> 6, l = t & 63;
  const int lr = l & 15, g = l >> 4;
  const int b0 = blockIdx.x * BT;
  const short* w1f  = (const short*)ws + OFF_W1F;
  const short* w2f  = (const short*)ws + OFF_W2F;
  const short* vw1f = (const short*)ws + OFF_VW1F;
  const short* kwf  = (const short*)ws + OFF_KWF;

  // ---- A-fragments: wave w owns rows w*16..w*16+15 (64 VGPR) ----
  short8v aF[16];
  {
    const float* srow = states + (size_t)(b0 + w * 16 + lr) * (AA * SS);
    #pragma unroll
    for (int f = 0; f < 16; ++f) {
      float4 p0 = *(const float4*)(srow + f * 32 + g * 8);
      float4 p1 = *(const float4*)(srow + f * 32 + g * 8 + 4);
      short8v a;
      a[0] = (short)f2bf(p0.x); a[1] = (short)f2bf(p0.y);
      a[2] = (short)f2bf(p0.z); a[3] = (short)f2bf(p0.w);
      a[4] = (short)f2bf(p1.x); a[5] = (short)f2bf(p1.y);
      a[6] = (short)f2bf(p1.z); a[7] = (short)f2bf(p1.w);
      aF[f] = a;
    }
  }

  for (int h = 0; h < HH; ++h) {
    f32x4 acc2[4] = {{0,0,0,0},{0,0,0,0},{0,0,0,0},{0,0,0,0}};  // P2 acc (K=256)
    for (int hf = 0; hf < 2; ++hf) {
      // ---- P1 half: 8 f-tiles staged through Bst, depth-1 pipelined ----
      const short* w1h = w1f + (size_t)(h * 256 + hf * 128) * 512;
      short8v stgA[4], stgB[4];
      P1_LOAD(stgA, 0);
      #pragma unroll
      for (int ft2 = 0; ft2 < 4; ++ft2) {
        __syncthreads();                    // previous tile's readers done
        P1_WRITE(stgA);
        __syncthreads();                    // staged tile visible
        P1_LOAD(stgB, ft2 * 2 + 1);         // overlaps with MFMAs below
        P1_COMPUTE(ft2 * 2);
        __syncthreads();
        P1_WRITE(stgB);
        __syncthreads();
        if (ft2 < 3) P1_LOAD(stgA, ft2 * 2 + 2);
        P1_COMPUTE(ft2 * 2 + 1);
      }
      // ---- P2 partial: acc2 += hmid(half) @ sel_w2[h][half] ----
      {
        const short* ah = hmid + (w * 16 + lr) * 136 + g * 8;
        const short* b2 = w2f + (size_t)(h * 32 + hf * 4) * 512 + l * 8;
        #pragma unroll
        for (int kf = 0; kf < 4; ++kf) {
          short8v afh = *(const short8v*)(ah + kf * 32);
          #pragma unroll
          for (int et = 0; et < 4; ++et)
            acc2[et] = __builtin_amdgcn_mfma_f32_16x16x32_bf16(
                afh, *(const short8v*)(b2 + (size_t)(et * 8 + kf) * 512),
                acc2[et], 0, 0, 0);
        }
      }
      __syncthreads();                      // hmid reads done before overwrite
    }
    // ---- write sel ----
    #pragma unroll
    for (int et = 0; et < 4; ++et)
      #pragma unroll
      for (int r2 = 0; r2 < 4; ++r2)
        sel[(w * 16 + g * 4 + r2) * 72 + et * 16 + lr] =
            (short)f2bf(acc2[et][r2]);
    __syncthreads();
    // ---- P3: m = sel @ key_w[h]^T (direct B, 8KB) ----
    {
      f32x4 a3[4] = {{0,0,0,0},{0,0,0,0},{0,0,0,0},{0,0,0,0}};
      const short* as_ = sel + (w * 16 + lr) * 72 + g * 8;
      const short* b3 = kwf + (size_t)(h * 8) * 512 + l * 8;
      #pragma unroll
      for (int kf = 0; kf < 2; ++kf) {
        short8v af3 = *(const short8v*)(as_ + kf * 32);
        #pragma unroll
        for (int ut = 0; ut < 4; ++ut)
          a3[ut] = __builtin_amdgcn_mfma_f32_16x16x32_bf16(
              af3, *(const short8v*)(b3 + (size_t)(ut * 2 + kf) * 512),
              a3[ut], 0, 0, 0);
      }
      #pragma unroll
      for (int ut = 0; ut < 4; ++ut)
        #pragma unroll
        for (int r2 = 0; r2 < 4; ++r2)
          mh[(w * 16 + g * 4 + r2) * 72 + ut * 16 + lr] =
              (short)f2bf(a3[ut][r2]);
    }
    __syncthreads();
    // ---- P4h: logits from registers (static aF indices, R7-proven) ----
    {
      const short* mrow = mh + (w * 16 + lr) * 72;
      short8v mv0 = *(const short8v*)(mrow + g * 8);
      short8v mv1 = *(const short8v*)(mrow + 32 + g * 8);
      #pragma unroll
      for (int a = 0; a < 8; ++a) {          // compile-time constant
        short8v a0 = aF[a * 2], a1 = aF[a * 2 + 1];
        float p = 0.f;
        #pragma unroll
        for (int j = 0; j < 8; ++j)
          p += bf2f(a0[j]) * bf2f(mv0[j]) + bf2f(a1[j]) * bf2f(mv1[j]);
        p += __shfl_xor(p, 16);
        p += __shfl_xor(p, 32);
        if (g == 0) logitsL[(w * 16 + lr) * 33 + h * 8 + a] = p;
      }
    }
    // no barrier: next h touches Bst first (1 barrier before its ds_write);
    // mh next written by next P3 (>=3 barriers away); hmid by next P1_COMPUTE
    // (>=2 barriers after this h's P2 reads).
  }

  // ---- P1v: vhid = relu(st @ v_w1 + b1); direct B (64KB/wave) ----
  {
    f32x4 av[4] = {{0,0,0,0},{0,0,0,0},{0,0,0,0},{0,0,0,0}};
    const short* bv = vw1f + l * 8;
    #pragma unroll
    for (int kf = 0; kf < 16; ++kf) {
      short8v af = aF[kf];
      #pragma unroll
      for (int et = 0; et < 4; ++et)
        av[et] = __builtin_amdgcn_mfma_f32_16x16x32_bf16(
            af, *(const short8v*)(bv + (size_t)(et * 16 + kf) * 512),
            av[et], 0, 0, 0);
    }
    #pragma unroll
    for (int et = 0; et < 4; ++et) {
      float bias = v_b1[et * 16 + lr];
      #pragma unroll
      for (int r2 = 0; r2 < 4; ++r2)
        vhid[(w * 16 + g * 4 + r2) * 72 + et * 16 + lr] =
            (short)f2bf(fmaxf(av[et][r2] + bias, 0.f));
    }
  }
  __syncthreads();

  // ---- v finalize (2 passes over 64 rows) ----
  #pragma unroll
  for (int i = 0; i < 2; ++i) {
    int b = i * 32 + (t >> 3), r = t & 7;
    short8v hv = *(const short8v*)(vhid + b * 72 + r * 8);
    float p = 0.f;
    #pragma unroll
    for (int j = 0; j < 8; ++j) p += bf2f(hv[j]) * v_w2[r * 8 + j];
    p += __shfl_xor(p, 1); p += __shfl_xor(p, 2); p += __shfl_xor(p, 4);
    if (r == 0) out[OUTV + b0 + b] = p + v_b2[0];
  }

  // ---- P5: softmax, entropy, reg — all 256 threads = 64 rows x 4 heads ----
  {
    int b = t >> 2, hh = t & 3;
    float sc[8];
    float rp = 0.f, mx = -1e30f;
    #pragma unroll
    for (int a = 0; a < 8; ++a) {
      float lg = logitsL[b * 33 + hh * 8 + a];
      rp += lg * lg;
      sc[a] = lg * 0.125f;
      mx = fmaxf(mx, sc[a]);
    }
    float sum = 0.f;
    #pragma unroll
    for (int a = 0; a < 8; ++a) { sc[a] = __expf(sc[a] - mx); sum += sc[a]; }
    float inv = 1.f / sum, ent = 0.f;
    #pragma unroll
    for (int a = 0; a < 8; ++a) {
      float wv = sc[a] * inv;
      wtsL[b * 33 + hh * 8 + a] = wv;
      ent += wv * __logf(wv + 1e-8f);
    }
    #pragma unroll
    for (int off = 1; off <= 32; off <<= 1) rp += __shfl_xor(rp, off);
    if (l == 0)
      atomicAdd(out + OUTR, rp * (0.001f / ((float)BB * (float)AA)));
    float ep = ent;
    #pragma unroll
    for (int off = 4; off <= 32; off <<= 1) ep += __shfl_xor(ep, off);
    if (l < 4) atomicAdd(out + OUTE + l, -ep / (float)BB);
  }
  __syncthreads();
  // ---- head_attend: 64 rows x 8 agents ----
  #pragma unroll
  for (int i = 0; i < 2; ++i) {
    int o = i * 256 + t, b = o >> 3, a = o & 7;
    out[(size_t)(b0 + b) * AA + a] = wtsL[b * 33 + a] + wtsL[b * 33 + 8 + a] +
                                     wtsL[b * 33 + 16 + a] + wtsL[b * 33 + 24 + a];
  }
}

extern "C" void kernel_launch(void* const* d_in, const int* in_sizes, int n_in,
                              void* d_out, int out_size, void* d_ws, size_t ws_size,
                              hipStream_t stream) {
  (void)in_sizes; (void)n_in; (void)ws_size; (void)out_size;
  const float* states = (const float*)d_in[1];
  const float* sel_w1 = (const float*)d_in[3];
  const float* sel_b1 = (const float*)d_in[4];
  const float* sel_w2 = (const float*)d_in[5];
  const float* key_w  = (const float*)d_in[6];
  const float* v_w1   = (const float*)d_in[7];
  const float* v_b1   = (const float*)d_in[8];
  const float* v_w2   = (const float*)d_in[9];
  const float* v_b2   = (const float*)d_in[10];
  float* out = (float*)d_out;
  unsigned short* ws = (unsigned short*)d_ws;

  hipMemsetAsync(out + OUTR, 0, 5 * sizeof(float), stream);
  prep_kernel<<<(PREP_N + 255) / 256, 256, 0, stream>>>(sel_w1, sel_w2, v_w1,
                                                        key_w, ws);
  qatten_mfma<<<BB / BT, 256, 0, stream>>>(states, sel_b1, v_b1, v_w2, v_b2,
                                           ws, out);
}

// Round 9
// 118.296 us; speedup vs baseline: 2.1133x; 1.1268x over previous
//
#include <hip/hip_runtime.h>
#include <stdint.h>

// Qatten_Weight — Round 9: R4 champion + ONE change: non-temporal states
// loads (+ non-temporal output stores). Theory: the 33.5MB states stream
// thrashes the per-XCD L2 and evicts the 1.25MB packed weights, so P1's
// B-fragment loads pay L3/HBM latency (~600-900cyc) instead of L2 (~225cyc)
// — which is why runtime tracks in-flight-load count (R4 13-deep=117us,
// R7 7-deep=190us). nt loads keep st from allocating hot in L2.
// Everything else is R4 VERBATIM (proven 117us, absmax 3.9e-3).
// B=16384 A=8 S=512 U=64 H=4 E=64 HE=256; BT=32, grid 512 x 256 threads.

typedef __attribute__((ext_vector_type(8))) short short8v;  // 8 bf16
typedef __attribute__((ext_vector_type(4))) float f32x4;
typedef __attribute__((ext_vector_type(4))) float f4v;

constexpr int BB = 16384, AA = 8, SS = 512, UU = 64, HH = 4, EE = 64, HE = 256;
constexpr int BT = 32;
constexpr int OUTV = BB * AA, OUTR = OUTV + BB, OUTE = OUTR + 1;

// packed fragment regions in ws (bf16 element offsets); frag = 512 elems = 1KB
constexpr int OFF_W1F  = 0;        // sel_w1: frag = h*256 + ftile*16 + kf   (1024)
constexpr int OFF_W2F  = 524288;   // sel_w2: frag = h*32  + etile*8  + kf   (128)
constexpr int OFF_VW1F = 589824;   // v_w1:   frag = etile*16 + kf           (64)
constexpr int OFF_KWF  = 622592;   // key_w:  frag = h*8 + utile*2 + kf      (32)
constexpr int PREP_N   = 638976;

__device__ __forceinline__ unsigned short f2bf(float x) {
  union { float f; uint32_t u; } v; v.f = x;
  uint32_t r = v.u + 0x7fffu + ((v.u >> 16) & 1u);   // RNE
  return (unsigned short)(r >> 16);
}
__device__ __forceinline__ float bf2f(short h) {
  union { uint32_t u; float f; } v; v.u = ((uint32_t)(unsigned short)h) << 16;
  return v.f;
}

// Pack: within a frag, element r = l*8 + j holds B[k = kf*32 + (l>>4)*8 + j]
// [col = tile*16 + (l&15)] — exactly the 16x16x32 B-fragment lane layout.
__global__ __launch_bounds__(256) void prep_kernel(
    const float* __restrict__ w1, const float* __restrict__ w2,
    const float* __restrict__ vw1, const float* __restrict__ kw,
    unsigned short* __restrict__ ws) {
  int idx = blockIdx.x * 256 + threadIdx.x;
  if (idx >= PREP_N) return;
  int r = idx & 511, l = r >> 3, j = r & 7, lr = l & 15, g = l >> 4;
  int fi = idx >> 9;
  float val;
  if (idx < OFF_W2F) {                    // B[k=s][col=f] for P1
    int h = fi >> 8, tl = (fi >> 4) & 15, kf = fi & 15;
    int s = kf * 32 + g * 8 + j, f = tl * 16 + lr;
    val = w1[((size_t)(h * SS) + s) * HE + f];
  } else if (idx < OFF_VW1F) {            // B[k=f][col=e] for P2
    fi -= OFF_W2F >> 9;
    int h = fi >> 5, tl = (fi >> 3) & 3, kf = fi & 7;
    int k = kf * 32 + g * 8 + j, e = tl * 16 + lr;
    val = w2[((size_t)(h * HE) + k) * EE + e];
  } else if (idx < OFF_KWF) {             // B[k=s][col=e] for P1v
    fi -= OFF_VW1F >> 9;
    int tl = fi >> 4, kf = fi & 15;
    int s = kf * 32 + g * 8 + j, e = tl * 16 + lr;
    val = vw1[(size_t)s * EE + e];
  } else {                                // B[k=e][col=u] for P3
    fi -= OFF_KWF >> 9;
    int h = fi >> 3, tl = (fi >> 1) & 3, kf = fi & 1;
    int k = kf * 32 + g * 8 + j, u = tl * 16 + lr;
    val = kw[((size_t)(h * UU) + u) * EE + k];
  }
  ws[idx] = f2bf(val);
}

__global__ __launch_bounds__(256) void qatten_mfma(
    const float* __restrict__ states, const float* __restrict__ sel_b1,
    const float* __restrict__ v_b1,  const float* __restrict__ v_w2,
    const float* __restrict__ v_b2,  const unsigned short* __restrict__ ws,
    float* __restrict__ out) {
  __shared__ __align__(16) unsigned char lds[63232];
  short* hmid = (short*)lds;                 // [32][264] bf16 (per-head)
  short* sel  = (short*)(lds + 16896);       // [32][72]  bf16 (per-head)
  short* stl  = (short*)lds;                 // [32][520] bf16 (P4 alias)
  short* mm   = (short*)(lds + 33280);       // [32][264] bf16 (all heads)
  short* vhid = (short*)(lds + 50176);       // [32][72]  bf16
  float* logitsL = (float*)(lds + 54784);    // [32][33]
  float* wtsL    = (float*)(lds + 59008);    // [32][33]

  const int t  = threadIdx.x;
  const int w  = t >> 6, l = t & 63;
  const int mt = w & 1, nh = w >> 1;         // M-tile, N-half (R2/R4 mapping)
  const int lr = l & 15, g = l >> 4;
  const int b0 = blockIdx.x * BT;
  const short* w1f  = (const short*)ws + OFF_W1F;
  const short* w2f  = (const short*)ws + OFF_W2F;
  const short* vw1f = (const short*)ws + OFF_VW1F;
  const short* kwf  = (const short*)ws + OFF_KWF;

  // ---- A-fragments: 16 rows of st, bf16, in registers; NON-TEMPORAL ----
  short8v aF[16];
  {
    const float* srow = states + (size_t)(b0 + mt * 16 + lr) * (AA * SS);
    #pragma unroll
    for (int f = 0; f < 16; ++f) {
      f4v p0 = __builtin_nontemporal_load((const f4v*)(srow + f * 32 + g * 8));
      f4v p1 = __builtin_nontemporal_load((const f4v*)(srow + f * 32 + g * 8 + 4));
      short8v a;
      a[0] = (short)f2bf(p0[0]); a[1] = (short)f2bf(p0[1]);
      a[2] = (short)f2bf(p0[2]); a[3] = (short)f2bf(p0[3]);
      a[4] = (short)f2bf(p1[0]); a[5] = (short)f2bf(p1[1]);
      a[6] = (short)f2bf(p1[2]); a[7] = (short)f2bf(p1[3]);
      aF[f] = a;
    }
  }

  for (int h = 0; h < HH; ++h) {
    // ---- P1: hmid = relu(st @ sel_w1[h] + b1); K-outer, 8 indep accs ----
    f32x4 acc[8] = {{0,0,0,0},{0,0,0,0},{0,0,0,0},{0,0,0,0},
                    {0,0,0,0},{0,0,0,0},{0,0,0,0},{0,0,0,0}};
    {
      const short* bb = w1f + ((size_t)(h * 256 + nh * 128)) * 512 + l * 8;
      #pragma unroll
      for (int kf = 0; kf < 16; ++kf) {
        short8v af = aF[kf];
        #pragma unroll
        for (int tl = 0; tl < 8; ++tl)
          acc[tl] = __builtin_amdgcn_mfma_f32_16x16x32_bf16(
              af, *(const short8v*)(bb + (size_t)(tl * 16 + kf) * 512),
              acc[tl], 0, 0, 0);
      }
    }
    #pragma unroll
    for (int tl = 0; tl < 8; ++tl) {
      int fb = (nh * 8 + tl) * 16;
      float bias = sel_b1[h * HE + fb + lr];
      #pragma unroll
      for (int r2 = 0; r2 < 4; ++r2)
        hmid[(mt * 16 + g * 4 + r2) * 264 + fb + lr] =
            (short)f2bf(fmaxf(acc[tl][r2] + bias, 0.f));
    }
    __syncthreads();

    // ---- P2: sel = hmid @ sel_w2[h]; K-outer, 2 indep accs, K=256 ----
    f32x4 a2[2] = {{0,0,0,0},{0,0,0,0}};
    {
      const short* ah = hmid + (mt * 16 + lr) * 264 + g * 8;
      const short* b2 = w2f + ((size_t)(h * 32 + nh * 16)) * 512 + l * 8;
      #pragma unroll
      for (int kf = 0; kf < 8; ++kf) {
        short8v af = *(const short8v*)(ah + kf * 32);
        #pragma unroll
        for (int tl = 0; tl < 2; ++tl)
          a2[tl] = __builtin_amdgcn_mfma_f32_16x16x32_bf16(
              af, *(const short8v*)(b2 + (size_t)(tl * 8 + kf) * 512),
              a2[tl], 0, 0, 0);
      }
    }
    #pragma unroll
    for (int tl = 0; tl < 2; ++tl)
      #pragma unroll
      for (int r2 = 0; r2 < 4; ++r2)
        sel[(mt * 16 + g * 4 + r2) * 72 + (nh * 2 + tl) * 16 + lr] =
            (short)f2bf(a2[tl][r2]);
    __syncthreads();

    // ---- P3: m = sel @ key_w[h]^T; K-outer, 2 indep accs, K=64 ----
    f32x4 a3[2] = {{0,0,0,0},{0,0,0,0}};
    {
      const short* as = sel + (mt * 16 + lr) * 72 + g * 8;
      const short* b3 = kwf + ((size_t)(h * 8 + nh * 4)) * 512 + l * 8;
      #pragma unroll
      for (int kf = 0; kf < 2; ++kf) {
        short8v af = *(const short8v*)(as + kf * 32);
        #pragma unroll
        for (int tl = 0; tl < 2; ++tl)
          a3[tl] = __builtin_amdgcn_mfma_f32_16x16x32_bf16(
              af, *(const short8v*)(b3 + (size_t)(tl * 2 + kf) * 512),
              a3[tl], 0, 0, 0);
      }
    }
    #pragma unroll
    for (int tl = 0; tl < 2; ++tl)
      #pragma unroll
      for (int r2 = 0; r2 < 4; ++r2)
        mm[(mt * 16 + g * 4 + r2) * 264 + h * 64 + (nh * 2 + tl) * 16 + lr] =
            (short)f2bf(a3[tl][r2]);
    __syncthreads();   // also guards hmid overwrite by next head's P1
  }

  // ---- P1v: vhid = relu(st @ v_w1 + b1); K-outer, 2 indep accs ----
  {
    f32x4 av[2] = {{0,0,0,0},{0,0,0,0}};
    const short* bv = vw1f + ((size_t)(nh * 32)) * 512 + l * 8;
    #pragma unroll
    for (int kf = 0; kf < 16; ++kf) {
      short8v af = aF[kf];
      #pragma unroll
      for (int tl = 0; tl < 2; ++tl)
        av[tl] = __builtin_amdgcn_mfma_f32_16x16x32_bf16(
            af, *(const short8v*)(bv + (size_t)(tl * 16 + kf) * 512),
            av[tl], 0, 0, 0);
    }
    #pragma unroll
    for (int tl = 0; tl < 2; ++tl) {
      int eb = (nh * 2 + tl) * 16;
      float bias = v_b1[eb + lr];
      #pragma unroll
      for (int r2 = 0; r2 < 4; ++r2)
        vhid[(mt * 16 + g * 4 + r2) * 72 + eb + lr] =
            (short)f2bf(fmaxf(av[tl][r2] + bias, 0.f));
    }
  }
  __syncthreads();

  // ---- v finalize (reads vhid) + stage st into LDS (R4 verbatim) ----
  {
    int b = t >> 3, r = t & 7;
    short8v hv = *(const short8v*)(vhid + b * 72 + r * 8);
    float p = 0.f;
    #pragma unroll
    for (int j = 0; j < 8; ++j) p += bf2f(hv[j]) * v_w2[r * 8 + j];
    p += __shfl_xor(p, 1); p += __shfl_xor(p, 2); p += __shfl_xor(p, 4);
    if (r == 0)
      __builtin_nontemporal_store(p + v_b2[0], out + OUTV + b0 + b);
  }
  if (w < 2) {                         // waves 0,1 dump A-frags: rows 0..31
    #pragma unroll
    for (int f = 0; f < 16; ++f)
      *(short8v*)(stl + (w * 16 + lr) * 520 + f * 32 + g * 8) = aF[f];
  }
  __syncthreads();

  // ---- P4: logits[b,h,a] = sum_u st[b][a*64+u] * m[b][h*64+u] ----
  #pragma unroll
  for (int i = 0; i < 4; ++i) {
    int o = t + 256 * i;
    int b = o >> 5, hh = (o >> 3) & 3, a = o & 7;
    float lg = 0.f;
    #pragma unroll
    for (int j = 0; j < 8; ++j) {
      short8v s8 = *(const short8v*)(stl + b * 520 + a * 64 + j * 8);
      short8v m8 = *(const short8v*)(mm + b * 264 + hh * 64 + j * 8);
      #pragma unroll
      for (int q = 0; q < 8; ++q) lg += bf2f(s8[q]) * bf2f(m8[q]);
    }
    logitsL[b * 33 + hh * 8 + a] = lg;
  }
  __syncthreads();

  // ---- P5: softmax, entropy, reg (R4 verbatim) ----
  if (t < 128) {
    int b = t >> 2, hh = t & 3;
    float sc[8];
    float rp = 0.f, mx = -1e30f;
    #pragma unroll
    for (int a = 0; a < 8; ++a) {
      float lg = logitsL[b * 33 + hh * 8 + a];
      rp += lg * lg;
      sc[a] = lg * 0.125f;
      mx = fmaxf(mx, sc[a]);
    }
    float sum = 0.f;
    #pragma unroll
    for (int a = 0; a < 8; ++a) { sc[a] = __expf(sc[a] - mx); sum += sc[a]; }
    float inv = 1.f / sum, ent = 0.f;
    #pragma unroll
    for (int a = 0; a < 8; ++a) {
      float wv = sc[a] * inv;
      wtsL[b * 33 + hh * 8 + a] = wv;
      ent += wv * __logf(wv + 1e-8f);
    }
    #pragma unroll
    for (int off = 1; off <= 32; off <<= 1) rp += __shfl_xor(rp, off);
    if ((t & 63) == 0)
      atomicAdd(out + OUTR, rp * (0.001f / ((float)BB * (float)AA)));
    float ep = ent;
    #pragma unroll
    for (int off = 4; off <= 32; off <<= 1) ep += __shfl_xor(ep, off);
    if ((t & 63) < 4) atomicAdd(out + OUTE + hh, -ep / (float)BB);
  }
  __syncthreads();
  {
    int b = t >> 3, a = t & 7;
    float s = wtsL[b * 33 + a] + wtsL[b * 33 + 8 + a] +
              wtsL[b * 33 + 16 + a] + wtsL[b * 33 + 24 + a];
    __builtin_nontemporal_store(s, out + (size_t)(b0 + b) * AA + a);
  }
}

extern "C" void kernel_launch(void* const* d_in, const int* in_sizes, int n_in,
                              void* d_out, int out_size, void* d_ws, size_t ws_size,
                              hipStream_t stream) {
  (void)in_sizes; (void)n_in; (void)ws_size; (void)out_size;
  const float* states = (const float*)d_in[1];
  const float* sel_w1 = (const float*)d_in[3];
  const float* sel_b1 = (const float*)d_in[4];
  const float* sel_w2 = (const float*)d_in[5];
  const float* key_w  = (const float*)d_in[6];
  const float* v_w1   = (const float*)d_in[7];
  const float* v_b1   = (const float*)d_in[8];
  const float* v_w2   = (const float*)d_in[9];
  const float* v_b2   = (const float*)d_in[10];
  float* out = (float*)d_out;
  unsigned short* ws = (unsigned short*)d_ws;

  hipMemsetAsync(out + OUTR, 0, 5 * sizeof(float), stream);
  prep_kernel<<<(PREP_N + 255) / 256, 256, 0, stream>>>(sel_w1, sel_w2, v_w1,
                                                        key_w, ws);
  qatten_mfma<<<BB / BT, 256, 0, stream>>>(states, sel_b1, v_b1, v_w2, v_b2,
                                           ws, out);
}